// Round 11
// baseline (457.471 us; speedup 1.0000x reference)
//
#include <hip/hip_runtime.h>
#include <hip/hip_bf16.h>

#define N_ROWS 32768
#define K_CODES 4096
#define D_DIM 256
#define CAP 128
#define MARGIN_T 1e-3f
#define SLOTS 8

// ---- d_ws layout (bytes) -- total 4,882,432 ----
#define WS_COUNTS    0          // float[4096]
#define WS_LOSSP     16384      // float[32768]
#define WS_IDX       147456     // int[32768]
#define WS_Z2        278528     // float[32768]
#define WS_E2        409600     // float[4096]
#define WS_DW        688128     // float[1048576] -> ends 4882432

// ---- d_out scratch (all regions consumed by rescore before k3/k4/k5 rewrite) ----
#define DO_ZB        0          // ushort[32768*256] = 16 MB (panel layout)
#define DO_WB        16777216   // ushort[4096*256]  =  2 MB (panel layout)
#define DO_CAND      18874368   // uint[32768][16][8] = 16 MB -> ends 35651584
#define DO_CNT8      35651584   // uchar[32768][16]  = 512 KB -> ends 36175872
#define DO_LMAX      36175872   // float[32768][16]  =   2 MB -> ends 38273024 (< 42.09 MB)

typedef __attribute__((ext_vector_type(8)))  short bf16x8;
typedef __attribute__((ext_vector_type(16))) float f32x16;
typedef __attribute__((ext_vector_type(8)))  unsigned short us8;

// ---------------------------------------------------------------------------
// K1: z2/e2 with numpy's exact pairwise structure (proven in R1)
// ---------------------------------------------------------------------------
__global__ void k1_norms(const float* __restrict__ z, const float* __restrict__ w,
                         float* __restrict__ z2, float* __restrict__ e2)
{
#pragma clang fp contract(off)
    int gid = blockIdx.x * blockDim.x + threadIdx.x;
    const float* row;
    float* outp;
    if (gid < N_ROWS) { row = z + (size_t)gid * D_DIM; outp = z2 + gid; }
    else if (gid < N_ROWS + K_CODES) { row = w + (size_t)(gid - N_ROWS) * D_DIM; outp = e2 + (gid - N_ROWS); }
    else return;

    float total = 0.0f;
    for (int half = 0; half < 2; half++) {
        const float* x = row + half * 128;
        float r[8];
#pragma unroll
        for (int j = 0; j < 8; j++) { float v = x[j]; r[j] = v * v; }
        for (int i = 8; i < 128; i += 8) {
#pragma unroll
            for (int j = 0; j < 8; j++) { float v = x[i + j]; r[j] += v * v; }
        }
        float s = ((r[0] + r[1]) + (r[2] + r[3])) + ((r[4] + r[5]) + (r[6] + r[7]));
        if (half == 0) total = s; else total = total + s;
    }
    *outp = total;
}

// ---------------------------------------------------------------------------
// KCONV v2 (proven R4): fp32 -> bf16 (RNE) in "LDS-image" PANEL layout so
// k2's staging is a straight contiguous copy. Bit-identical LDS bytes vs R3.
// ---------------------------------------------------------------------------
__device__ inline unsigned short f2b(float f) {
    __hip_bfloat16 h = __float2bfloat16(f);
    return *(unsigned short*)&h;
}

__global__ void kconv(const float* __restrict__ z, const float* __restrict__ w,
                      unsigned short* __restrict__ zb, unsigned short* __restrict__ wb)
{
    const int lane  = threadIdx.x & 63;
    const int gwave = blockIdx.x * 4 + (threadIdx.x >> 6);   // 0..4607
    const int kk    = gwave & 7;
    const int row   = (gwave >> 3) * 64 + lane;              // 0..36863
    const float* src;
    unsigned short* panel;
    int g;
    if (row < N_ROWS) {
        src   = z + (size_t)row * D_DIM;
        panel = zb + ((size_t)((row >> 8) * 8 + kk) << 13);
        g     = (row >> 5) & 7;
    } else {
        int c = row - N_ROWS;
        src   = w + (size_t)c * D_DIM;
        panel = wb + ((size_t)((c >> 8) * 8 + kk) << 13);
        g     = (c >> 5) & 7;
    }
    const int r31 = row & 31;
    const float* s0 = src + kk * 32;
#pragma unroll
    for (int s = 0; s < 2; s++)
#pragma unroll
        for (int h = 0; h < 2; h++) {
            float4 a = *(const float4*)(s0 + s * 16 + h * 8);
            float4 b = *(const float4*)(s0 + s * 16 + h * 8 + 4);
            us8 o;
            o[0] = f2b(a.x); o[1] = f2b(a.y); o[2] = f2b(a.z); o[3] = f2b(a.w);
            o[4] = f2b(b.x); o[5] = f2b(b.y); o[6] = f2b(b.z); o[7] = f2b(b.w);
            *(us8*)(panel + (((g * 2 + s) * 64 + h * 32 + r31) << 3)) = o;
        }
}

// ---------------------------------------------------------------------------
// async global->LDS, 16B per lane. LDS dest = wave-uniform base + lane*16.
// ---------------------------------------------------------------------------
__device__ inline void gload16(const void* g, void* l)
{
    __builtin_amdgcn_global_load_lds(
        (const __attribute__((address_space(1))) unsigned int*)g,
        (__attribute__((address_space(3))) unsigned int*)l,
        16, 0, 0);
}

// ---------------------------------------------------------------------------
// K2 v5.1 (REVERTED to the proven R9 config -- 131us, MfmaUtil 21.5%):
// 256x256-tile bf16 MFMA GEMM, 512 thr = 8 waves (2x4), wave tile 128x64 =
// acc[4][2]. R10's 4-wave/acc[4][4] variant hit the 256-VGPR occupancy
// cliff (1 wave/SIMD, MfmaUtil 14.3%, 197us) -- ILP gained < TLP lost.
// This config is VGPR-limited at ~2 waves/SIMD (208 regs/wave) and sits
// near the 2-barrier structure's ceiling for K=256.
// Atomic-free append (LDS-atomic slot reservation, per-(row,cb) 8-slot
// regions, plain stores) + exact fp32 block-local row max to lmax.
// ---------------------------------------------------------------------------
__global__ __launch_bounds__(512, 2) void k2_scan(
    const unsigned short* __restrict__ zb, const unsigned short* __restrict__ wb,
    unsigned char* __restrict__ cnt8, unsigned int* __restrict__ cand2,
    float* __restrict__ lmax)
{
    __shared__ char smem[65536];
    const int tid  = threadIdx.x;
    const int lane = tid & 63;
    const int wid  = tid >> 6;     // 0..7
    const int wm   = wid >> 2;     // code-wave 0..1
    const int wn   = wid & 3;      // row-wave 0..3
    const int m    = lane & 31;
    const int half = lane >> 5;

    // bijective XCD swizzle: XCD(r_hw) == o/256 (proven R3/R4: FETCH 17MB)
    const int r_hw = blockIdx.y * 16 + blockIdx.x;
    const int o    = (r_hw & 7) * 256 + (r_hw >> 3);
    const int cb   = o & 15;       // code-block 0..15
    const int rb   = o >> 4;       // row-block  0..127
    const int rowBase  = rb * 256;
    const int codeBase = cb * 256;

    // linear panel copy: A panel (wb) and B panel (zb) for window kk.
    auto stage = [&](int kk, int buf) {
        char* Ab = smem + buf * 32768;
        char* Bb = Ab + 16384;
        const unsigned short* Ap = wb + ((size_t)(cb * 8 + kk) << 13);
        const unsigned short* Bp = zb + ((size_t)(rb * 8 + kk) << 13);
#pragma unroll
        for (int i = 0; i < 2; i++) {
            gload16(Ap + (size_t)((i * 512 + tid) << 3), Ab + (size_t)(i * 512 + tid) * 16);
            gload16(Bp + (size_t)((i * 512 + tid) << 3), Bb + (size_t)(i * 512 + tid) * 16);
        }
    };

    f32x16 acc[4][2];
    {
        f32x16 zz = {};
#pragma unroll
        for (int ms = 0; ms < 4; ms++)
#pragma unroll
            for (int ns = 0; ns < 2; ns++) acc[ms][ns] = zz;
    }

    stage(0, 0);

    for (int kk = 0; kk < 8; kk++) {
        const int buf = kk & 1;
        __syncthreads();                       // drains vmcnt -> buf ready
        if (kk + 1 < 8) stage(kk + 1, buf ^ 1);
        const char* Ab = smem + buf * 32768;
        const char* Bb = Ab + 16384;
#pragma unroll
        for (int s = 0; s < 2; s++) {
            bf16x8 af[4], bfr[2];
#pragma unroll
            for (int ms = 0; ms < 4; ms++)
                af[ms] = *(const bf16x8*)(Ab + (size_t)(((wm * 4 + ms) * 2 + s) * 64 + lane) * 16);
#pragma unroll
            for (int ns = 0; ns < 2; ns++)
                bfr[ns] = *(const bf16x8*)(Bb + (size_t)(((wn * 2 + ns) * 2 + s) * 64 + lane) * 16);
#pragma unroll
            for (int ms = 0; ms < 4; ms++)
#pragma unroll
                for (int ns = 0; ns < 2; ns++)
                    acc[ms][ns] = __builtin_amdgcn_mfma_f32_32x32x16_bf16(
                        af[ms], bfr[ns], acc[ms][ns], 0, 0, 0);
        }
    }

    // ---- epilogue: block-local per-row max over all 256 codes ----
    float tmax[2] = {-1e30f, -1e30f};
#pragma unroll
    for (int ms = 0; ms < 4; ms++)
#pragma unroll
        for (int ns = 0; ns < 2; ns++)
#pragma unroll
            for (int r = 0; r < 16; r++)
                tmax[ns] = fmaxf(tmax[ns], acc[ms][ns][r]);
#pragma unroll
    for (int ns = 0; ns < 2; ns++)
        tmax[ns] = fmaxf(tmax[ns], __shfl_xor(tmax[ns], 32));

    __syncthreads();                 // GEMM LDS dead; reuse for rowmax + lcnt
    float* rmx  = (float*)smem;      // [2][256]: [wm][local row]
    int*   lcnt = (int*)(smem + 2048);   // [256] per-row slot counters
    if (lane < 32) {
        rmx[wm * 256 + wn * 64 + 0 * 32 + lane] = tmax[0];
        rmx[wm * 256 + wn * 64 + 1 * 32 + lane] = tmax[1];
    }
    if (tid < 256) lcnt[tid] = 0;
    __syncthreads();

    float thr[2];
#pragma unroll
    for (int ns = 0; ns < 2; ns++) {
        const int lr = wn * 64 + ns * 32 + m;
        thr[ns] = fmaxf(rmx[lr], rmx[256 + lr]) - MARGIN_T;
    }

    // ---- append keepers: LDS-atomic slot reservation + plain stores ----
#pragma unroll
    for (int ms = 0; ms < 4; ms++)
#pragma unroll
        for (int ns = 0; ns < 2; ns++)
#pragma unroll
            for (int r = 0; r < 16; r++) {
                float v = acc[ms][ns][r];
                if (v >= thr[ns]) {
                    const int lr = wn * 64 + ns * 32 + m;
                    int slot = atomicAdd(&lcnt[lr], 1);        // LDS atomic
                    if (slot < SLOTS) {
                        int code = codeBase + wm * 128 + ms * 32
                                 + ((r & 3) + 8 * (r >> 2) + 4 * half);
                        int b = __float_as_int(v);
                        unsigned key = (unsigned)b ^ ((unsigned)(b >> 31) | 0x80000000u);
                        unsigned entry = (key & 0xFFFFF000u) | (unsigned)code;
                        cand2[((size_t)(rowBase + lr) * 16 + cb) * SLOTS + slot] = entry;
                    }
                }
            }

    __syncthreads();
    if (tid < 256) {
        int cf = lcnt[tid];
        cnt8[(size_t)(rowBase + tid) * 16 + cb] =
            (cf > SLOTS) ? (unsigned char)255 : (unsigned char)cf;
        lmax[(size_t)(rowBase + tid) * 16 + cb] = fmaxf(rmx[tid], rmx[256 + tid]);
    }
}

// ---------------------------------------------------------------------------
// K_RESCORE v10 (unchanged from R9): 4 rows per 256-thread block (one WAVE
// per row), zero __syncthreads. Gather+filter vs exact global max from lmax;
// per-block exact recovery of qualifying overflow blocks (cnt8==255 AND
// lmax >= gm-MARGIN). Proven R9: rescore left the top-5.
// ---------------------------------------------------------------------------
__global__ __launch_bounds__(256) void k_rescore(
    const float* __restrict__ z, const float* __restrict__ w,
    const float* __restrict__ z2, const float* __restrict__ e2,
    const unsigned char* __restrict__ cnt8, const unsigned int* __restrict__ cand2,
    const float* __restrict__ lmax, int* __restrict__ idx_out)
{
#pragma clang fp contract(off)
    const int lane = threadIdx.x & 63;
    const int wv   = threadIdx.x >> 6;          // 0..3
    const int n    = blockIdx.x * 4 + wv;

    __shared__ float4 zst[4][64];               // 4 KB, wave-private slices
    __shared__ int    surv[4][CAP];             // 2 KB, wave-private slices

    zst[wv][lane] = ((const float4*)(z + (size_t)n * D_DIM))[lane];

    // ---- counts + exact global row max ----
    int   c  = 0;
    float lm = -1e30f;
    if (lane < 16) {
        c  = cnt8[(size_t)n * 16 + lane];
        lm = lmax[(size_t)n * 16 + lane];
    }
    float gm = lm;
#pragma unroll
    for (int off = 32; off > 0; off >>= 1)
        gm = fmaxf(gm, __shfl_xor(gm, off));    // wave-uniform exact max

    // mask of qualifying overflow blocks (bits 0..15); wave-uniform
    unsigned long long obal =
        __ballot((lane < 16) && (c == 255) && (lm >= gm - MARGIN_T));

    float bd = __builtin_inff(); int bk = K_CODES;
    const float z2v = z2[n];

    // ---- coalesced full-slice gather + filter (always) ----
    {
        const unsigned e0 = cand2[(size_t)n * 128 + lane];
        const unsigned e1 = cand2[(size_t)n * 128 + 64 + lane];
        const int craw0 = __shfl(c, lane >> 3);           // cb0 = lane>>3 (0..7)
        const int craw1 = __shfl(c, 8 + (lane >> 3));     // cb1 = 8+(lane>>3)
        const int cl0 = (craw0 == 255) ? SLOTS : craw0;
        const int cl1 = (craw1 == 255) ? SLOTS : craw1;
        const float thrF = gm - MARGIN_T - 1e-4f;         // key-truncation slack

        auto keyf = [](unsigned e) -> float {
            unsigned ky = e & 0xFFFFF000u;
            int b = (ky & 0x80000000u) ? (int)(ky ^ 0x80000000u) : (int)~ky;
            return __int_as_float(b);
        };
        const bool keep0 = ((lane & 7) < cl0) && (keyf(e0) >= thrF);
        const bool keep1 = ((lane & 7) < cl1) && (keyf(e1) >= thrF);

        unsigned long long bal0 = __ballot(keep0);
        unsigned long long bal1 = __ballot(keep1);
        const unsigned long long below = (1ull << lane) - 1ull;
        const int n0 = (int)__popcll(bal0);
        if (keep0) surv[wv][(int)__popcll(bal0 & below)] = (int)(e0 & 0xFFFu);
        if (keep1) surv[wv][n0 + (int)__popcll(bal1 & below)] = (int)(e1 & 0xFFFu);
        const int nt = n0 + (int)__popcll(bal1);

        // ---- per-lane exact survivor chains (nt typically 1-3) ----
        for (int s = lane; s < nt; s += 64) {
            int k = surv[wv][s];
            if ((unsigned)k >= (unsigned)K_CODES) k = 0;  // defensive
            const float4* wp = (const float4*)(w + (size_t)k * D_DIM);
            float tacc = 0.0f;
#pragma unroll 8
            for (int d4 = 0; d4 < 64; d4++) {
                float4 wvv = wp[d4];
                float4 zv  = zst[wv][d4];
                tacc = __builtin_fmaf(zv.x, wvv.x, tacc);
                tacc = __builtin_fmaf(zv.y, wvv.y, tacc);
                tacc = __builtin_fmaf(zv.z, wvv.z, tacc);
                tacc = __builtin_fmaf(zv.w, wvv.w, tacc);
            }
            float u  = z2v - 2.0f * tacc;   // 2*tacc exact -> single rounding
            float dv = u + e2[k];
            if (dv < bd || (dv == bd && k < bk)) { bd = dv; bk = k; }
        }
    }

    // ---- per-block exact recovery of qualifying overflow blocks (rare) ----
    while (obal) {
        const int cbq = (int)(__ffsll((long long)obal) - 1);
        obal &= obal - 1ull;
        const int k0 = cbq * 256 + lane;      // lane's 4 codes: +0,+64,+128,+192
        const float4* w0 = (const float4*)(w + (size_t)(k0      ) * D_DIM);
        const float4* w1 = (const float4*)(w + (size_t)(k0 +  64) * D_DIM);
        const float4* w2 = (const float4*)(w + (size_t)(k0 + 128) * D_DIM);
        const float4* w3 = (const float4*)(w + (size_t)(k0 + 192) * D_DIM);
        float t0 = 0.0f, t1 = 0.0f, t2 = 0.0f, t3 = 0.0f;
#pragma unroll 8
        for (int d4 = 0; d4 < 64; d4++) {
            float4 zv = zst[wv][d4];          // LDS broadcast
            float4 a0 = w0[d4];
            float4 a1 = w1[d4];
            float4 a2 = w2[d4];
            float4 a3 = w3[d4];
            t0 = __builtin_fmaf(zv.x, a0.x, t0);
            t1 = __builtin_fmaf(zv.x, a1.x, t1);
            t2 = __builtin_fmaf(zv.x, a2.x, t2);
            t3 = __builtin_fmaf(zv.x, a3.x, t3);
            t0 = __builtin_fmaf(zv.y, a0.y, t0);
            t1 = __builtin_fmaf(zv.y, a1.y, t1);
            t2 = __builtin_fmaf(zv.y, a2.y, t2);
            t3 = __builtin_fmaf(zv.y, a3.y, t3);
            t0 = __builtin_fmaf(zv.z, a0.z, t0);
            t1 = __builtin_fmaf(zv.z, a1.z, t1);
            t2 = __builtin_fmaf(zv.z, a2.z, t2);
            t3 = __builtin_fmaf(zv.z, a3.z, t3);
            t0 = __builtin_fmaf(zv.w, a0.w, t0);
            t1 = __builtin_fmaf(zv.w, a1.w, t1);
            t2 = __builtin_fmaf(zv.w, a2.w, t2);
            t3 = __builtin_fmaf(zv.w, a3.w, t3);
        }
        float d0 = (z2v - 2.0f * t0) + e2[k0];
        float d1 = (z2v - 2.0f * t1) + e2[k0 + 64];
        float d2 = (z2v - 2.0f * t2) + e2[k0 + 128];
        float d3 = (z2v - 2.0f * t3) + e2[k0 + 192];
        if (d0 < bd || (d0 == bd && k0       < bk)) { bd = d0; bk = k0; }
        if (d1 < bd || (d1 == bd && k0 +  64 < bk)) { bd = d1; bk = k0 + 64; }
        if (d2 < bd || (d2 == bd && k0 + 128 < bk)) { bd = d2; bk = k0 + 128; }
        if (d3 < bd || (d3 == bd && k0 + 192 < bk)) { bd = d3; bk = k0 + 192; }
    }

#pragma unroll
    for (int off = 1; off < 64; off <<= 1) {
        float od = __shfl_xor(bd, off);
        int   ok = __shfl_xor(bk, off);
        if (od < bd || (od == bd && ok < bk)) { bd = od; bk = ok; }
    }
    if (lane == 0) idx_out[n] = (bk < K_CODES) ? bk : 0;
}

// ---------------------------------------------------------------------------
// K3 v2: wave-per-row (4 rows per 256-thread block), zero __syncthreads.
// Each lane owns a float4 (4 dims): coalesced 1KB/wave loads of z and
// w[idx], float4 zq store with the IDENTICAL zv+(wq-zv) per-element
// rounding, per-lane sq partial + __shfl_xor wave sum for lossp (reorders
// a 256-term fp32 positive sum: ~1e-9 change in the single loss scalar).
// dw atomics: same addresses/values as before (4 per lane), order already
// nondeterministic. Replaces the 8-barrier LDS tree + block-per-row launch.
// ---------------------------------------------------------------------------
__global__ __launch_bounds__(256) void k3_scatter(
    const float* __restrict__ z, const float* __restrict__ w,
    const int* __restrict__ idx_in,
    float* __restrict__ counts, float* __restrict__ lossp,
    float* __restrict__ dw, float* __restrict__ out_zq,
    float* __restrict__ out_idx)
{
#pragma clang fp contract(off)
    const int lane = threadIdx.x & 63;
    const int wv   = threadIdx.x >> 6;          // 0..3
    const int n    = blockIdx.x * 4 + wv;

    int idx = idx_in[n];                        // wave-uniform -> scalar load
    if (idx < 0) idx = 0;
    if (idx >= K_CODES) idx = K_CODES - 1;      // defensive clamp (no fault)

    float4 zv = ((const float4*)(z + (size_t)n   * D_DIM))[lane];
    float4 wq = ((const float4*)(w + (size_t)idx * D_DIM))[lane];

    float4 q;
    q.x = zv.x + (wq.x - zv.x);
    q.y = zv.y + (wq.y - zv.y);
    q.z = zv.z + (wq.z - zv.z);
    q.w = zv.w + (wq.w - zv.w);
    ((float4*)(out_zq + (size_t)n * D_DIM))[lane] = q;

    float dx = zv.x - wq.x, dy = zv.y - wq.y, dz = zv.z - wq.z, dwc = zv.w - wq.w;
    float sq = ((dx * dx + dy * dy) + (dz * dz + dwc * dwc));

    float* dwp = dw + (size_t)idx * D_DIM + lane * 4;
    atomicAdd(dwp + 0, zv.x);
    atomicAdd(dwp + 1, zv.y);
    atomicAdd(dwp + 2, zv.z);
    atomicAdd(dwp + 3, zv.w);

#pragma unroll
    for (int off = 1; off < 64; off <<= 1)
        sq += __shfl_xor(sq, off);

    if (lane == 0) {
        out_idx[n] = (float)idx;
        atomicAdd(&counts[idx], 1.0f);
        lossp[n] = sq;
    }
}

// ---------------------------------------------------------------------------
// K4: vq_loss finalize + new_cs (Laplace smoothing). Single block, 1024 thr.
// ---------------------------------------------------------------------------
__global__ void k4_cs(const float* __restrict__ lossp, const float* __restrict__ counts,
                      const float* __restrict__ cs_in, float* __restrict__ out_loss,
                      float* __restrict__ out_cs)
{
#pragma clang fp contract(off)
    const int t = threadIdx.x;
    __shared__ float red[1024];
    __shared__ float pre[K_CODES];

    float s = 0.0f;
    for (int i = t; i < N_ROWS; i += 1024) s += lossp[i];
    red[t] = s; __syncthreads();
    for (int st = 512; st > 0; st >>= 1) {
        if (t < st) red[t] += red[t + st];
        __syncthreads();
    }
    if (t == 0) out_loss[0] = 0.25f * (red[0] / 8388608.0f);
    __syncthreads();

    const float DEC = 0.99f;
    const float OMD = (float)(1.0 - 0.99);
    float mine[4];
#pragma unroll
    for (int q = 0; q < 4; q++) {
        int k = t + q * 1024;
        float t1 = DEC * cs_in[k];
        float t2 = OMD * counts[k];
        float p = t1 + t2;
        pre[k] = p; mine[q] = p;
    }
    float psum = (mine[0] + mine[1]) + (mine[2] + mine[3]);
    red[t] = psum; __syncthreads();
    for (int st = 512; st > 0; st >>= 1) {
        if (t < st) red[t] += red[t + st];
        __syncthreads();
    }
    float nsum = red[0];
    const float KEPS = (float)(4096.0 * 1e-5);
    float denom = nsum + KEPS;
#pragma unroll
    for (int q = 0; q < 4; q++) {
        int k = t + q * 1024;
        float v = ((pre[k] + 1e-5f) / denom) * nsum;
        out_cs[k] = v;
    }
}

// ---------------------------------------------------------------------------
// K5: new_ema_w = 0.99*ema_w + 0.01*dw ; new_weight = new_ema_w / new_cs[k]
// ---------------------------------------------------------------------------
__global__ void k5_emaw(const float* __restrict__ ema_w, const float* __restrict__ dw,
                        const float* __restrict__ newcs, float* __restrict__ out_w,
                        float* __restrict__ out_emaw)
{
#pragma clang fp contract(off)
    const int i = blockIdx.x * 256 + threadIdx.x;
    const int k = i >> 8;
    const float OMD = (float)(1.0 - 0.99);
    float t1 = 0.99f * ema_w[i];
    float t2 = OMD * dw[i];
    float ne = t1 + t2;
    out_emaw[i] = ne;
    out_w[i] = ne / newcs[k];
}

extern "C" void kernel_launch(void* const* d_in, const int* in_sizes, int n_in,
                              void* d_out, int out_size, void* d_ws, size_t ws_size,
                              hipStream_t stream)
{
    const float* z    = (const float*)d_in[0];
    const float* w    = (const float*)d_in[1];
    const float* cs   = (const float*)d_in[2];
    const float* emaw = (const float*)d_in[3];

    float* out      = (float*)d_out;
    float* out_zq   = out;                    // 8388608
    float* out_idx  = out + 8388608;          // 32768
    float* out_loss = out + 8421376;          // 1
    float* out_w    = out + 8421377;          // 1048576
    float* out_cs   = out + 9469953;          // 4096
    float* out_emaw = out + 9474049;          // 1048576

    char* ws = (char*)d_ws;
    float*          counts  = (float*)(ws + WS_COUNTS);
    float*          lossp   = (float*)(ws + WS_LOSSP);
    int*            idx_int = (int*)  (ws + WS_IDX);
    float*          z2      = (float*)(ws + WS_Z2);
    float*          e2      = (float*)(ws + WS_E2);
    float*          dw      = (float*)(ws + WS_DW);

    // big scratch lives in d_out (consumed by rescore before k3/k4/k5 rewrite it)
    char* ob = (char*)d_out;
    unsigned short* zb    = (unsigned short*)(ob + DO_ZB);
    unsigned short* wb    = (unsigned short*)(ob + DO_WB);
    unsigned int*   cand2 = (unsigned int*)  (ob + DO_CAND);
    unsigned char*  cnt8  = (unsigned char*) (ob + DO_CNT8);
    float*          lmx   = (float*)         (ob + DO_LMAX);

    hipMemsetAsync(counts, 0, K_CODES * sizeof(float), stream);
    hipMemsetAsync(dw, 0, (size_t)K_CODES * D_DIM * sizeof(float), stream);

    k1_norms<<<(N_ROWS + K_CODES) / 256, 256, 0, stream>>>(z, w, z2, e2);

    // 4608 waves: (36864 rows / 64 rows-per-wave) * 8 kk-panels; 4 waves/block
    kconv<<<1152, 256, 0, stream>>>(z, w, zb, wb);

    dim3 g2(16, 128);   // x = code-block, y = row-block (swizzled in-kernel)
    k2_scan<<<g2, 512, 0, stream>>>(zb, wb, cnt8, cand2, lmx);

    // 4 rows per 256-thread block (one wave per row)
    k_rescore<<<N_ROWS / 4, 256, 0, stream>>>(z, w, z2, e2, cnt8, cand2, lmx, idx_int);

    // 4 rows per 256-thread block (one wave per row)
    k3_scatter<<<N_ROWS / 4, 256, 0, stream>>>(z, w, idx_int, counts, lossp,
                                               dw, out_zq, out_idx);

    k4_cs<<<1, 1024, 0, stream>>>(lossp, counts, cs, out_loss, out_cs);

    k5_emaw<<<K_CODES, 256, 0, stream>>>(emaw, dw, out_cs, out_w, out_emaw);
}

// Round 12
// 381.422 us; speedup vs baseline: 1.1994x; 1.1994x over previous
//
#include <hip/hip_runtime.h>
#include <hip/hip_bf16.h>

#define N_ROWS 32768
#define K_CODES 4096
#define D_DIM 256
#define CAP 128
#define MARGIN_T 1e-3f
#define SLOTS 8

// ---- d_ws layout (bytes) -- total 4,882,432 ----
#define WS_COUNTS    0          // (legacy float[4096], unused)
#define WS_LOSSP     16384      // float[32768]
#define WS_IDX       147456     // int[32768]
#define WS_Z2        278528     // float[32768]
#define WS_E2        409600     // float[4096]
#define WS_CCOUNT    425984     // int[4096]   (inverted index: per-code count)
#define WS_STARTS    442368     // int[4096]   (exclusive prefix)
#define WS_CURSOR    458752     // int[4096]   (fill cursors)
#define WS_ROWS      475136     // int[32768]  -> ends 606208 (< 688128 WS_DW)
#define WS_DW        688128     // (legacy float[1048576], unused)

// ---- d_out scratch (all regions consumed by rescore before k3/k4/k5 rewrite) ----
#define DO_ZB        0          // ushort[32768*256] = 16 MB (panel layout)
#define DO_WB        16777216   // ushort[4096*256]  =  2 MB (panel layout)
#define DO_CAND      18874368   // uint[32768][16][8] = 16 MB -> ends 35651584
#define DO_CNT8      35651584   // uchar[32768][16]  = 512 KB -> ends 36175872
#define DO_LMAX      36175872   // float[32768][16]  =   2 MB -> ends 38273024 (< 42.09 MB)

typedef __attribute__((ext_vector_type(8)))  short bf16x8;
typedef __attribute__((ext_vector_type(16))) float f32x16;
typedef __attribute__((ext_vector_type(8)))  unsigned short us8;

// ---------------------------------------------------------------------------
// K1: z2/e2 with numpy's exact pairwise structure (proven in R1)
// ---------------------------------------------------------------------------
__global__ void k1_norms(const float* __restrict__ z, const float* __restrict__ w,
                         float* __restrict__ z2, float* __restrict__ e2)
{
#pragma clang fp contract(off)
    int gid = blockIdx.x * blockDim.x + threadIdx.x;
    const float* row;
    float* outp;
    if (gid < N_ROWS) { row = z + (size_t)gid * D_DIM; outp = z2 + gid; }
    else if (gid < N_ROWS + K_CODES) { row = w + (size_t)(gid - N_ROWS) * D_DIM; outp = e2 + (gid - N_ROWS); }
    else return;

    float total = 0.0f;
    for (int half = 0; half < 2; half++) {
        const float* x = row + half * 128;
        float r[8];
#pragma unroll
        for (int j = 0; j < 8; j++) { float v = x[j]; r[j] = v * v; }
        for (int i = 8; i < 128; i += 8) {
#pragma unroll
            for (int j = 0; j < 8; j++) { float v = x[i + j]; r[j] += v * v; }
        }
        float s = ((r[0] + r[1]) + (r[2] + r[3])) + ((r[4] + r[5]) + (r[6] + r[7]));
        if (half == 0) total = s; else total = total + s;
    }
    *outp = total;
}

// ---------------------------------------------------------------------------
// KCONV v2 (proven R4): fp32 -> bf16 (RNE) in "LDS-image" PANEL layout so
// k2's staging is a straight contiguous copy. Bit-identical LDS bytes vs R3.
// ---------------------------------------------------------------------------
__device__ inline unsigned short f2b(float f) {
    __hip_bfloat16 h = __float2bfloat16(f);
    return *(unsigned short*)&h;
}

__global__ void kconv(const float* __restrict__ z, const float* __restrict__ w,
                      unsigned short* __restrict__ zb, unsigned short* __restrict__ wb)
{
    const int lane  = threadIdx.x & 63;
    const int gwave = blockIdx.x * 4 + (threadIdx.x >> 6);   // 0..4607
    const int kk    = gwave & 7;
    const int row   = (gwave >> 3) * 64 + lane;              // 0..36863
    const float* src;
    unsigned short* panel;
    int g;
    if (row < N_ROWS) {
        src   = z + (size_t)row * D_DIM;
        panel = zb + ((size_t)((row >> 8) * 8 + kk) << 13);
        g     = (row >> 5) & 7;
    } else {
        int c = row - N_ROWS;
        src   = w + (size_t)c * D_DIM;
        panel = wb + ((size_t)((c >> 8) * 8 + kk) << 13);
        g     = (c >> 5) & 7;
    }
    const int r31 = row & 31;
    const float* s0 = src + kk * 32;
#pragma unroll
    for (int s = 0; s < 2; s++)
#pragma unroll
        for (int h = 0; h < 2; h++) {
            float4 a = *(const float4*)(s0 + s * 16 + h * 8);
            float4 b = *(const float4*)(s0 + s * 16 + h * 8 + 4);
            us8 o;
            o[0] = f2b(a.x); o[1] = f2b(a.y); o[2] = f2b(a.z); o[3] = f2b(a.w);
            o[4] = f2b(b.x); o[5] = f2b(b.y); o[6] = f2b(b.z); o[7] = f2b(b.w);
            *(us8*)(panel + (((g * 2 + s) * 64 + h * 32 + r31) << 3)) = o;
        }
}

// ---------------------------------------------------------------------------
// async global->LDS, 16B per lane. LDS dest = wave-uniform base + lane*16.
// ---------------------------------------------------------------------------
__device__ inline void gload16(const void* g, void* l)
{
    __builtin_amdgcn_global_load_lds(
        (const __attribute__((address_space(1))) unsigned int*)g,
        (__attribute__((address_space(3))) unsigned int*)l,
        16, 0, 0);
}

// ---------------------------------------------------------------------------
// K2 v5.1 (proven R9/R11 -- 129-131us, MfmaUtil 21.5%): 256x256-tile bf16
// MFMA GEMM, 512 thr = 8 waves (2x4), wave tile 128x64 = acc[4][2].
// Atomic-free append (LDS-atomic slot reservation, per-(row,cb) 8-slot
// regions, plain stores) + exact fp32 block-local row max to lmax.
// ---------------------------------------------------------------------------
__global__ __launch_bounds__(512, 2) void k2_scan(
    const unsigned short* __restrict__ zb, const unsigned short* __restrict__ wb,
    unsigned char* __restrict__ cnt8, unsigned int* __restrict__ cand2,
    float* __restrict__ lmax)
{
    __shared__ char smem[65536];
    const int tid  = threadIdx.x;
    const int lane = tid & 63;
    const int wid  = tid >> 6;     // 0..7
    const int wm   = wid >> 2;     // code-wave 0..1
    const int wn   = wid & 3;      // row-wave 0..3
    const int m    = lane & 31;
    const int half = lane >> 5;

    // bijective XCD swizzle: XCD(r_hw) == o/256 (proven R3/R4: FETCH 17MB)
    const int r_hw = blockIdx.y * 16 + blockIdx.x;
    const int o    = (r_hw & 7) * 256 + (r_hw >> 3);
    const int cb   = o & 15;       // code-block 0..15
    const int rb   = o >> 4;       // row-block  0..127
    const int rowBase  = rb * 256;
    const int codeBase = cb * 256;

    // linear panel copy: A panel (wb) and B panel (zb) for window kk.
    auto stage = [&](int kk, int buf) {
        char* Ab = smem + buf * 32768;
        char* Bb = Ab + 16384;
        const unsigned short* Ap = wb + ((size_t)(cb * 8 + kk) << 13);
        const unsigned short* Bp = zb + ((size_t)(rb * 8 + kk) << 13);
#pragma unroll
        for (int i = 0; i < 2; i++) {
            gload16(Ap + (size_t)((i * 512 + tid) << 3), Ab + (size_t)(i * 512 + tid) * 16);
            gload16(Bp + (size_t)((i * 512 + tid) << 3), Bb + (size_t)(i * 512 + tid) * 16);
        }
    };

    f32x16 acc[4][2];
    {
        f32x16 zz = {};
#pragma unroll
        for (int ms = 0; ms < 4; ms++)
#pragma unroll
            for (int ns = 0; ns < 2; ns++) acc[ms][ns] = zz;
    }

    stage(0, 0);

    for (int kk = 0; kk < 8; kk++) {
        const int buf = kk & 1;
        __syncthreads();                       // drains vmcnt -> buf ready
        if (kk + 1 < 8) stage(kk + 1, buf ^ 1);
        const char* Ab = smem + buf * 32768;
        const char* Bb = Ab + 16384;
#pragma unroll
        for (int s = 0; s < 2; s++) {
            bf16x8 af[4], bfr[2];
#pragma unroll
            for (int ms = 0; ms < 4; ms++)
                af[ms] = *(const bf16x8*)(Ab + (size_t)(((wm * 4 + ms) * 2 + s) * 64 + lane) * 16);
#pragma unroll
            for (int ns = 0; ns < 2; ns++)
                bfr[ns] = *(const bf16x8*)(Bb + (size_t)(((wn * 2 + ns) * 2 + s) * 64 + lane) * 16);
#pragma unroll
            for (int ms = 0; ms < 4; ms++)
#pragma unroll
                for (int ns = 0; ns < 2; ns++)
                    acc[ms][ns] = __builtin_amdgcn_mfma_f32_32x32x16_bf16(
                        af[ms], bfr[ns], acc[ms][ns], 0, 0, 0);
        }
    }

    // ---- epilogue: block-local per-row max over all 256 codes ----
    float tmax[2] = {-1e30f, -1e30f};
#pragma unroll
    for (int ms = 0; ms < 4; ms++)
#pragma unroll
        for (int ns = 0; ns < 2; ns++)
#pragma unroll
            for (int r = 0; r < 16; r++)
                tmax[ns] = fmaxf(tmax[ns], acc[ms][ns][r]);
#pragma unroll
    for (int ns = 0; ns < 2; ns++)
        tmax[ns] = fmaxf(tmax[ns], __shfl_xor(tmax[ns], 32));

    __syncthreads();                 // GEMM LDS dead; reuse for rowmax + lcnt
    float* rmx  = (float*)smem;      // [2][256]: [wm][local row]
    int*   lcnt = (int*)(smem + 2048);   // [256] per-row slot counters
    if (lane < 32) {
        rmx[wm * 256 + wn * 64 + 0 * 32 + lane] = tmax[0];
        rmx[wm * 256 + wn * 64 + 1 * 32 + lane] = tmax[1];
    }
    if (tid < 256) lcnt[tid] = 0;
    __syncthreads();

    float thr[2];
#pragma unroll
    for (int ns = 0; ns < 2; ns++) {
        const int lr = wn * 64 + ns * 32 + m;
        thr[ns] = fmaxf(rmx[lr], rmx[256 + lr]) - MARGIN_T;
    }

    // ---- append keepers: LDS-atomic slot reservation + plain stores ----
#pragma unroll
    for (int ms = 0; ms < 4; ms++)
#pragma unroll
        for (int ns = 0; ns < 2; ns++)
#pragma unroll
            for (int r = 0; r < 16; r++) {
                float v = acc[ms][ns][r];
                if (v >= thr[ns]) {
                    const int lr = wn * 64 + ns * 32 + m;
                    int slot = atomicAdd(&lcnt[lr], 1);        // LDS atomic
                    if (slot < SLOTS) {
                        int code = codeBase + wm * 128 + ms * 32
                                 + ((r & 3) + 8 * (r >> 2) + 4 * half);
                        int b = __float_as_int(v);
                        unsigned key = (unsigned)b ^ ((unsigned)(b >> 31) | 0x80000000u);
                        unsigned entry = (key & 0xFFFFF000u) | (unsigned)code;
                        cand2[((size_t)(rowBase + lr) * 16 + cb) * SLOTS + slot] = entry;
                    }
                }
            }

    __syncthreads();
    if (tid < 256) {
        int cf = lcnt[tid];
        cnt8[(size_t)(rowBase + tid) * 16 + cb] =
            (cf > SLOTS) ? (unsigned char)255 : (unsigned char)cf;
        lmax[(size_t)(rowBase + tid) * 16 + cb] = fmaxf(rmx[tid], rmx[256 + tid]);
    }
}

// ---------------------------------------------------------------------------
// K_RESCORE v10 (unchanged, proven R9): 4 rows per 256-thread block (one
// WAVE per row), zero __syncthreads. Gather+filter vs exact global max from
// lmax; per-block exact recovery of qualifying overflow blocks.
// ---------------------------------------------------------------------------
__global__ __launch_bounds__(256) void k_rescore(
    const float* __restrict__ z, const float* __restrict__ w,
    const float* __restrict__ z2, const float* __restrict__ e2,
    const unsigned char* __restrict__ cnt8, const unsigned int* __restrict__ cand2,
    const float* __restrict__ lmax, int* __restrict__ idx_out)
{
#pragma clang fp contract(off)
    const int lane = threadIdx.x & 63;
    const int wv   = threadIdx.x >> 6;          // 0..3
    const int n    = blockIdx.x * 4 + wv;

    __shared__ float4 zst[4][64];               // 4 KB, wave-private slices
    __shared__ int    surv[4][CAP];             // 2 KB, wave-private slices

    zst[wv][lane] = ((const float4*)(z + (size_t)n * D_DIM))[lane];

    // ---- counts + exact global row max ----
    int   c  = 0;
    float lm = -1e30f;
    if (lane < 16) {
        c  = cnt8[(size_t)n * 16 + lane];
        lm = lmax[(size_t)n * 16 + lane];
    }
    float gm = lm;
#pragma unroll
    for (int off = 32; off > 0; off >>= 1)
        gm = fmaxf(gm, __shfl_xor(gm, off));    // wave-uniform exact max

    // mask of qualifying overflow blocks (bits 0..15); wave-uniform
    unsigned long long obal =
        __ballot((lane < 16) && (c == 255) && (lm >= gm - MARGIN_T));

    float bd = __builtin_inff(); int bk = K_CODES;
    const float z2v = z2[n];

    // ---- coalesced full-slice gather + filter (always) ----
    {
        const unsigned e0 = cand2[(size_t)n * 128 + lane];
        const unsigned e1 = cand2[(size_t)n * 128 + 64 + lane];
        const int craw0 = __shfl(c, lane >> 3);           // cb0 = lane>>3 (0..7)
        const int craw1 = __shfl(c, 8 + (lane >> 3));     // cb1 = 8+(lane>>3)
        const int cl0 = (craw0 == 255) ? SLOTS : craw0;
        const int cl1 = (craw1 == 255) ? SLOTS : craw1;
        const float thrF = gm - MARGIN_T - 1e-4f;         // key-truncation slack

        auto keyf = [](unsigned e) -> float {
            unsigned ky = e & 0xFFFFF000u;
            int b = (ky & 0x80000000u) ? (int)(ky ^ 0x80000000u) : (int)~ky;
            return __int_as_float(b);
        };
        const bool keep0 = ((lane & 7) < cl0) && (keyf(e0) >= thrF);
        const bool keep1 = ((lane & 7) < cl1) && (keyf(e1) >= thrF);

        unsigned long long bal0 = __ballot(keep0);
        unsigned long long bal1 = __ballot(keep1);
        const unsigned long long below = (1ull << lane) - 1ull;
        const int n0 = (int)__popcll(bal0);
        if (keep0) surv[wv][(int)__popcll(bal0 & below)] = (int)(e0 & 0xFFFu);
        if (keep1) surv[wv][n0 + (int)__popcll(bal1 & below)] = (int)(e1 & 0xFFFu);
        const int nt = n0 + (int)__popcll(bal1);

        // ---- per-lane exact survivor chains (nt typically 1-3) ----
        for (int s = lane; s < nt; s += 64) {
            int k = surv[wv][s];
            if ((unsigned)k >= (unsigned)K_CODES) k = 0;  // defensive
            const float4* wp = (const float4*)(w + (size_t)k * D_DIM);
            float tacc = 0.0f;
#pragma unroll 8
            for (int d4 = 0; d4 < 64; d4++) {
                float4 wvv = wp[d4];
                float4 zv  = zst[wv][d4];
                tacc = __builtin_fmaf(zv.x, wvv.x, tacc);
                tacc = __builtin_fmaf(zv.y, wvv.y, tacc);
                tacc = __builtin_fmaf(zv.z, wvv.z, tacc);
                tacc = __builtin_fmaf(zv.w, wvv.w, tacc);
            }
            float u  = z2v - 2.0f * tacc;   // 2*tacc exact -> single rounding
            float dv = u + e2[k];
            if (dv < bd || (dv == bd && k < bk)) { bd = dv; bk = k; }
        }
    }

    // ---- per-block exact recovery of qualifying overflow blocks (rare) ----
    while (obal) {
        const int cbq = (int)(__ffsll((long long)obal) - 1);
        obal &= obal - 1ull;
        const int k0 = cbq * 256 + lane;      // lane's 4 codes: +0,+64,+128,+192
        const float4* w0 = (const float4*)(w + (size_t)(k0      ) * D_DIM);
        const float4* w1 = (const float4*)(w + (size_t)(k0 +  64) * D_DIM);
        const float4* w2 = (const float4*)(w + (size_t)(k0 + 128) * D_DIM);
        const float4* w3 = (const float4*)(w + (size_t)(k0 + 192) * D_DIM);
        float t0 = 0.0f, t1 = 0.0f, t2 = 0.0f, t3 = 0.0f;
#pragma unroll 8
        for (int d4 = 0; d4 < 64; d4++) {
            float4 zv = zst[wv][d4];          // LDS broadcast
            float4 a0 = w0[d4];
            float4 a1 = w1[d4];
            float4 a2 = w2[d4];
            float4 a3 = w3[d4];
            t0 = __builtin_fmaf(zv.x, a0.x, t0);
            t1 = __builtin_fmaf(zv.x, a1.x, t1);
            t2 = __builtin_fmaf(zv.x, a2.x, t2);
            t3 = __builtin_fmaf(zv.x, a3.x, t3);
            t0 = __builtin_fmaf(zv.y, a0.y, t0);
            t1 = __builtin_fmaf(zv.y, a1.y, t1);
            t2 = __builtin_fmaf(zv.y, a2.y, t2);
            t3 = __builtin_fmaf(zv.y, a3.y, t3);
            t0 = __builtin_fmaf(zv.z, a0.z, t0);
            t1 = __builtin_fmaf(zv.z, a1.z, t1);
            t2 = __builtin_fmaf(zv.z, a2.z, t2);
            t3 = __builtin_fmaf(zv.z, a3.z, t3);
            t0 = __builtin_fmaf(zv.w, a0.w, t0);
            t1 = __builtin_fmaf(zv.w, a1.w, t1);
            t2 = __builtin_fmaf(zv.w, a2.w, t2);
            t3 = __builtin_fmaf(zv.w, a3.w, t3);
        }
        float d0 = (z2v - 2.0f * t0) + e2[k0];
        float d1 = (z2v - 2.0f * t1) + e2[k0 + 64];
        float d2 = (z2v - 2.0f * t2) + e2[k0 + 128];
        float d3 = (z2v - 2.0f * t3) + e2[k0 + 192];
        if (d0 < bd || (d0 == bd && k0       < bk)) { bd = d0; bk = k0; }
        if (d1 < bd || (d1 == bd && k0 +  64 < bk)) { bd = d1; bk = k0 + 64; }
        if (d2 < bd || (d2 == bd && k0 + 128 < bk)) { bd = d2; bk = k0 + 128; }
        if (d3 < bd || (d3 == bd && k0 + 192 < bk)) { bd = d3; bk = k0 + 192; }
    }

#pragma unroll
    for (int off = 1; off < 64; off <<= 1) {
        float od = __shfl_xor(bd, off);
        int   ok = __shfl_xor(bk, off);
        if (od < bd || (od == bd && ok < bk)) { bd = od; bk = ok; }
    }
    if (lane == 0) idx_out[n] = (bk < K_CODES) ? bk : 0;
}

// ---------------------------------------------------------------------------
// K_HIST: per-code int counts (32768 atomics, 16KB target -- cheap).
// ---------------------------------------------------------------------------
__global__ void k_hist(const int* __restrict__ idx_in, int* __restrict__ ccount)
{
    int n = blockIdx.x * 256 + threadIdx.x;
    int idx = idx_in[n];
    if (idx < 0) idx = 0;
    if (idx >= K_CODES) idx = K_CODES - 1;
    atomicAdd(&ccount[idx], 1);
}

// ---------------------------------------------------------------------------
// K_PREFIX: single block, exclusive prefix of ccount[4096] -> starts, cursor.
// ---------------------------------------------------------------------------
__global__ void k_prefix(const int* __restrict__ ccount,
                         int* __restrict__ starts, int* __restrict__ cursor)
{
    __shared__ int s[1024];
    const int t = threadIdx.x;
    int c0 = ccount[t * 4 + 0];
    int c1 = ccount[t * 4 + 1];
    int c2 = ccount[t * 4 + 2];
    int c3 = ccount[t * 4 + 3];
    int tsum = ((c0 + c1) + (c2 + c3));
    s[t] = tsum;
    __syncthreads();
    for (int off = 1; off < 1024; off <<= 1) {
        int v = (t >= off) ? s[t - off] : 0;
        __syncthreads();
        s[t] += v;
        __syncthreads();
    }
    int base = s[t] - tsum;          // exclusive
    starts[t * 4 + 0] = base;
    starts[t * 4 + 1] = base + c0;
    starts[t * 4 + 2] = base + c0 + c1;
    starts[t * 4 + 3] = base + c0 + c1 + c2;
    cursor[t * 4 + 0] = base;
    cursor[t * 4 + 1] = base + c0;
    cursor[t * 4 + 2] = base + c0 + c1;
    cursor[t * 4 + 3] = base + c0 + c1 + c2;
}

// ---------------------------------------------------------------------------
// K_FILL: bucket row ids (32768 atomics on cursor).
// ---------------------------------------------------------------------------
__global__ void k_fill(const int* __restrict__ idx_in, int* __restrict__ cursor,
                       int* __restrict__ rows)
{
    int n = blockIdx.x * 256 + threadIdx.x;
    int idx = idx_in[n];
    if (idx < 0) idx = 0;
    if (idx >= K_CODES) idx = K_CODES - 1;
    int pos = atomicAdd(&cursor[idx], 1);
    rows[pos] = n;
}

// ---------------------------------------------------------------------------
// K3 v3: block-per-row (R9-proven structure), NO atomics. zq store with
// identical zv+(wq-zv) rounding, identical LDS-tree loss reduction order.
// dw/counts moved to the inverted-index path (R11 post-mortem: the dw
// atomics were k3's dominant cost, ~85us delta between atomic layouts).
// ---------------------------------------------------------------------------
__global__ void k3_scatter(const float* __restrict__ z, const float* __restrict__ w,
                           const int* __restrict__ idx_in,
                           float* __restrict__ lossp, float* __restrict__ out_zq,
                           float* __restrict__ out_idx)
{
#pragma clang fp contract(off)
    const int n = blockIdx.x;
    const int t = threadIdx.x;
    int idx = idx_in[n];
    if (idx < 0) idx = 0;
    if (idx >= K_CODES) idx = K_CODES - 1;     // defensive clamp (no fault)
    if (t == 0) out_idx[n] = (float)idx;

    float zv = z[(size_t)n * D_DIM + t];
    float wq = w[(size_t)idx * D_DIM + t];
    out_zq[(size_t)n * D_DIM + t] = zv + (wq - zv);
    float df = zv - wq;
    float sq = df * df;

    __shared__ float red[256];
    red[t] = sq; __syncthreads();
    for (int s = 128; s > 0; s >>= 1) {
        if (t < s) red[t] += red[t + s];
        __syncthreads();
    }
    if (t == 0) lossp[n] = red[0];
}

// ---------------------------------------------------------------------------
// K4: vq_loss finalize + new_cs (Laplace smoothing). Single block, 1024 thr.
// counts now come from the exact int histogram (integer-valued, exact).
// ---------------------------------------------------------------------------
__global__ void k4_cs(const float* __restrict__ lossp, const int* __restrict__ ccount,
                      const float* __restrict__ cs_in, float* __restrict__ out_loss,
                      float* __restrict__ out_cs)
{
#pragma clang fp contract(off)
    const int t = threadIdx.x;
    __shared__ float red[1024];
    __shared__ float pre[K_CODES];

    float s = 0.0f;
    for (int i = t; i < N_ROWS; i += 1024) s += lossp[i];
    red[t] = s; __syncthreads();
    for (int st = 512; st > 0; st >>= 1) {
        if (t < st) red[t] += red[t + st];
        __syncthreads();
    }
    if (t == 0) out_loss[0] = 0.25f * (red[0] / 8388608.0f);
    __syncthreads();

    const float DEC = 0.99f;
    const float OMD = (float)(1.0 - 0.99);
    float mine[4];
#pragma unroll
    for (int q = 0; q < 4; q++) {
        int k = t + q * 1024;
        float t1 = DEC * cs_in[k];
        float t2 = OMD * (float)ccount[k];
        float p = t1 + t2;
        pre[k] = p; mine[q] = p;
    }
    float psum = (mine[0] + mine[1]) + (mine[2] + mine[3]);
    red[t] = psum; __syncthreads();
    for (int st = 512; st > 0; st >>= 1) {
        if (t < st) red[t] += red[t + st];
        __syncthreads();
    }
    float nsum = red[0];
    const float KEPS = (float)(4096.0 * 1e-5);
    float denom = nsum + KEPS;
#pragma unroll
    for (int q = 0; q < 4; q++) {
        int k = t + q * 1024;
        float v = ((pre[k] + 1e-5f) / denom) * nsum;
        out_cs[k] = v;
    }
}

// ---------------------------------------------------------------------------
// K5 v2: block-per-code gather-sum dw (replaces 8.4M float atomics).
// Thread t owns dim t; iterates the code's bucket rows with coalesced 1KB
// z-row reads, register accumulate (fp32 sum; order nondeterministic like
// the atomic version it replaces), then the identical EMA/divide.
// ---------------------------------------------------------------------------
__global__ void k5_emaw(const float* __restrict__ z, const float* __restrict__ ema_w,
                        const int* __restrict__ starts, const int* __restrict__ ccount,
                        const int* __restrict__ rows, const float* __restrict__ newcs,
                        float* __restrict__ out_w, float* __restrict__ out_emaw)
{
#pragma clang fp contract(off)
    const int k = blockIdx.x;
    const int t = threadIdx.x;
    const int s = starts[k];
    const int e = s + ccount[k];

    float acc = 0.0f;
    for (int r = s; r < e; r++) {
        int row = rows[r];
        acc += z[(size_t)row * D_DIM + t];
    }

    const float OMD = (float)(1.0 - 0.99);
    float t1 = 0.99f * ema_w[(size_t)k * D_DIM + t];
    float t2 = OMD * acc;
    float ne = t1 + t2;
    out_emaw[(size_t)k * D_DIM + t] = ne;
    out_w[(size_t)k * D_DIM + t] = ne / newcs[k];
}

extern "C" void kernel_launch(void* const* d_in, const int* in_sizes, int n_in,
                              void* d_out, int out_size, void* d_ws, size_t ws_size,
                              hipStream_t stream)
{
    const float* z    = (const float*)d_in[0];
    const float* w    = (const float*)d_in[1];
    const float* cs   = (const float*)d_in[2];
    const float* emaw = (const float*)d_in[3];

    float* out      = (float*)d_out;
    float* out_zq   = out;                    // 8388608
    float* out_idx  = out + 8388608;          // 32768
    float* out_loss = out + 8421376;          // 1
    float* out_w    = out + 8421377;          // 1048576
    float* out_cs   = out + 9469953;          // 4096
    float* out_emaw = out + 9474049;          // 1048576

    char* ws = (char*)d_ws;
    float*          lossp   = (float*)(ws + WS_LOSSP);
    int*            idx_int = (int*)  (ws + WS_IDX);
    float*          z2      = (float*)(ws + WS_Z2);
    float*          e2      = (float*)(ws + WS_E2);
    int*            ccount  = (int*)  (ws + WS_CCOUNT);
    int*            starts  = (int*)  (ws + WS_STARTS);
    int*            cursor  = (int*)  (ws + WS_CURSOR);
    int*            rowsb   = (int*)  (ws + WS_ROWS);

    // big scratch lives in d_out (consumed by rescore before k3/k4/k5 rewrite it)
    char* ob = (char*)d_out;
    unsigned short* zb    = (unsigned short*)(ob + DO_ZB);
    unsigned short* wb    = (unsigned short*)(ob + DO_WB);
    unsigned int*   cand2 = (unsigned int*)  (ob + DO_CAND);
    unsigned char*  cnt8  = (unsigned char*) (ob + DO_CNT8);
    float*          lmx   = (float*)         (ob + DO_LMAX);

    hipMemsetAsync(ccount, 0, K_CODES * sizeof(int), stream);

    k1_norms<<<(N_ROWS + K_CODES) / 256, 256, 0, stream>>>(z, w, z2, e2);

    // 4608 waves: (36864 rows / 64 rows-per-wave) * 8 kk-panels; 4 waves/block
    kconv<<<1152, 256, 0, stream>>>(z, w, zb, wb);

    dim3 g2(16, 128);   // x = code-block, y = row-block (swizzled in-kernel)
    k2_scan<<<g2, 512, 0, stream>>>(zb, wb, cnt8, cand2, lmx);

    // 4 rows per 256-thread block (one wave per row)
    k_rescore<<<N_ROWS / 4, 256, 0, stream>>>(z, w, z2, e2, cnt8, cand2, lmx, idx_int);

    // inverted index for dw gather-sum
    k_hist<<<N_ROWS / 256, 256, 0, stream>>>(idx_int, ccount);
    k_prefix<<<1, 1024, 0, stream>>>(ccount, starts, cursor);
    k_fill<<<N_ROWS / 256, 256, 0, stream>>>(idx_int, cursor, rowsb);

    k3_scatter<<<N_ROWS, 256, 0, stream>>>(z, w, idx_int, lossp, out_zq, out_idx);

    k4_cs<<<1, 1024, 0, stream>>>(lossp, ccount, cs, out_loss, out_cs);

    k5_emaw<<<K_CODES, 256, 0, stream>>>(z, emaw, starts, ccount, rowsb,
                                         out_cs, out_w, out_emaw);
}

// Round 14
// 368.333 us; speedup vs baseline: 1.2420x; 1.0355x over previous
//
#include <hip/hip_runtime.h>
#include <hip/hip_bf16.h>

#define N_ROWS 32768
#define K_CODES 4096
#define D_DIM 256
#define CAP 128
#define MARGIN_T 1e-3f
#define SLOTS 8

// ---- d_ws layout (bytes) -- total 4,882,432 ----
#define WS_LOSSP     16384      // float[32768]
#define WS_IDX       147456     // int[32768]
#define WS_Z2        278528     // float[32768]
#define WS_E2        409600     // float[4096]
#define WS_CCOUNT    425984     // int[4096]   (inverted index: per-code count)
#define WS_STARTS    442368     // int[4096]   (exclusive prefix)
#define WS_CURSOR    458752     // int[4096]   (fill cursors)
#define WS_ROWS      475136     // int[32768]  -> ends 606208

// ---- d_out scratch. ORDERING INVARIANT (R13 lesson): these regions alias
// out_zq/out_idx/out_w/out_emaw. NO kernel may write any d_out region until
// k_rescore (the last reader of cand2/cnt8/lmax) has fully completed.
#define DO_ZB        0          // ushort[32768*256] = 16 MB (panel layout)
#define DO_WB        16777216   // ushort[4096*256]  =  2 MB (panel layout)
#define DO_CAND      18874368   // uint[32768][16][8] = 16 MB -> ends 35651584
#define DO_CNT8      35651584   // uchar[32768][16]  = 512 KB -> ends 36175872
#define DO_LMAX      36175872   // float[32768][16]  =   2 MB -> ends 38273024 (< 42.09 MB)

typedef __attribute__((ext_vector_type(8)))  short bf16x8;
typedef __attribute__((ext_vector_type(16))) float f32x16;
typedef __attribute__((ext_vector_type(8)))  unsigned short us8;

// ---------------------------------------------------------------------------
// K1+KCONV fused (proven R12-R13 compile; range-split grid; both phases
// byte-identical to the proven standalone kernels). Blocks [0,145): k1
// z2/e2 (numpy's exact pairwise structure). Blocks [145,1297): kconv
// fp32->bf16 RNE in panel layout.
// ---------------------------------------------------------------------------
__device__ inline unsigned short f2b(float f) {
    __hip_bfloat16 h = __float2bfloat16(f);
    return *(unsigned short*)&h;
}

__global__ void k1_kconv(const float* __restrict__ z, const float* __restrict__ w,
                         float* __restrict__ z2, float* __restrict__ e2,
                         unsigned short* __restrict__ zb, unsigned short* __restrict__ wb)
{
#pragma clang fp contract(off)
    if (blockIdx.x < 145) {
        // ---- k1_norms ----
        int gid = blockIdx.x * blockDim.x + threadIdx.x;
        const float* row;
        float* outp;
        if (gid < N_ROWS) { row = z + (size_t)gid * D_DIM; outp = z2 + gid; }
        else if (gid < N_ROWS + K_CODES) { row = w + (size_t)(gid - N_ROWS) * D_DIM; outp = e2 + (gid - N_ROWS); }
        else return;

        float total = 0.0f;
        for (int half = 0; half < 2; half++) {
            const float* x = row + half * 128;
            float r[8];
#pragma unroll
            for (int j = 0; j < 8; j++) { float v = x[j]; r[j] = v * v; }
            for (int i = 8; i < 128; i += 8) {
#pragma unroll
                for (int j = 0; j < 8; j++) { float v = x[i + j]; r[j] += v * v; }
            }
            float s = ((r[0] + r[1]) + (r[2] + r[3])) + ((r[4] + r[5]) + (r[6] + r[7]));
            if (half == 0) total = s; else total = total + s;
        }
        *outp = total;
    } else {
        // ---- kconv ----
        const int bid   = blockIdx.x - 145;
        const int lane  = threadIdx.x & 63;
        const int gwave = bid * 4 + (threadIdx.x >> 6);   // 0..4607
        const int kk    = gwave & 7;
        const int row   = (gwave >> 3) * 64 + lane;       // 0..36863
        const float* src;
        unsigned short* panel;
        int g;
        if (row < N_ROWS) {
            src   = z + (size_t)row * D_DIM;
            panel = zb + ((size_t)((row >> 8) * 8 + kk) << 13);
            g     = (row >> 5) & 7;
        } else {
            int c = row - N_ROWS;
            src   = w + (size_t)c * D_DIM;
            panel = wb + ((size_t)((c >> 8) * 8 + kk) << 13);
            g     = (c >> 5) & 7;
        }
        const int r31 = row & 31;
        const float* s0 = src + kk * 32;
#pragma unroll
        for (int s = 0; s < 2; s++)
#pragma unroll
            for (int h = 0; h < 2; h++) {
                float4 a = *(const float4*)(s0 + s * 16 + h * 8);
                float4 b = *(const float4*)(s0 + s * 16 + h * 8 + 4);
                us8 o;
                o[0] = f2b(a.x); o[1] = f2b(a.y); o[2] = f2b(a.z); o[3] = f2b(a.w);
                o[4] = f2b(b.x); o[5] = f2b(b.y); o[6] = f2b(b.z); o[7] = f2b(b.w);
                *(us8*)(panel + (((g * 2 + s) * 64 + h * 32 + r31) << 3)) = o;
            }
    }
}

// ---------------------------------------------------------------------------
// async global->LDS, 16B per lane. LDS dest = wave-uniform base + lane*16.
// ---------------------------------------------------------------------------
__device__ inline void gload16(const void* g, void* l)
{
    __builtin_amdgcn_global_load_lds(
        (const __attribute__((address_space(1))) unsigned int*)g,
        (__attribute__((address_space(3))) unsigned int*)l,
        16, 0, 0);
}

// ---------------------------------------------------------------------------
// K2 v5.1 (proven R9/R11/R12 -- ~130us, MfmaUtil 21.5%): 256x256-tile bf16
// MFMA GEMM, 512 thr = 8 waves (2x4), wave tile 128x64 = acc[4][2].
// Atomic-free append (LDS-atomic slot reservation, per-(row,cb) 8-slot
// regions, plain stores) + exact fp32 block-local row max to lmax.
// ---------------------------------------------------------------------------
__global__ __launch_bounds__(512, 2) void k2_scan(
    const unsigned short* __restrict__ zb, const unsigned short* __restrict__ wb,
    unsigned char* __restrict__ cnt8, unsigned int* __restrict__ cand2,
    float* __restrict__ lmax)
{
    __shared__ char smem[65536];
    const int tid  = threadIdx.x;
    const int lane = tid & 63;
    const int wid  = tid >> 6;     // 0..7
    const int wm   = wid >> 2;     // code-wave 0..1
    const int wn   = wid & 3;      // row-wave 0..3
    const int m    = lane & 31;
    const int half = lane >> 5;

    // bijective XCD swizzle: XCD(r_hw) == o/256 (proven R3/R4: FETCH 17MB)
    const int r_hw = blockIdx.y * 16 + blockIdx.x;
    const int o    = (r_hw & 7) * 256 + (r_hw >> 3);
    const int cb   = o & 15;       // code-block 0..15
    const int rb   = o >> 4;       // row-block  0..127
    const int rowBase  = rb * 256;
    const int codeBase = cb * 256;

    // linear panel copy: A panel (wb) and B panel (zb) for window kk.
    auto stage = [&](int kk, int buf) {
        char* Ab = smem + buf * 32768;
        char* Bb = Ab + 16384;
        const unsigned short* Ap = wb + ((size_t)(cb * 8 + kk) << 13);
        const unsigned short* Bp = zb + ((size_t)(rb * 8 + kk) << 13);
#pragma unroll
        for (int i = 0; i < 2; i++) {
            gload16(Ap + (size_t)((i * 512 + tid) << 3), Ab + (size_t)(i * 512 + tid) * 16);
            gload16(Bp + (size_t)((i * 512 + tid) << 3), Bb + (size_t)(i * 512 + tid) * 16);
        }
    };

    f32x16 acc[4][2];
    {
        f32x16 zz = {};
#pragma unroll
        for (int ms = 0; ms < 4; ms++)
#pragma unroll
            for (int ns = 0; ns < 2; ns++) acc[ms][ns] = zz;
    }

    stage(0, 0);

    for (int kk = 0; kk < 8; kk++) {
        const int buf = kk & 1;
        __syncthreads();                       // drains vmcnt -> buf ready
        if (kk + 1 < 8) stage(kk + 1, buf ^ 1);
        const char* Ab = smem + buf * 32768;
        const char* Bb = Ab + 16384;
#pragma unroll
        for (int s = 0; s < 2; s++) {
            bf16x8 af[4], bfr[2];
#pragma unroll
            for (int ms = 0; ms < 4; ms++)
                af[ms] = *(const bf16x8*)(Ab + (size_t)(((wm * 4 + ms) * 2 + s) * 64 + lane) * 16);
#pragma unroll
            for (int ns = 0; ns < 2; ns++)
                bfr[ns] = *(const bf16x8*)(Bb + (size_t)(((wn * 2 + ns) * 2 + s) * 64 + lane) * 16);
#pragma unroll
            for (int ms = 0; ms < 4; ms++)
#pragma unroll
                for (int ns = 0; ns < 2; ns++)
                    acc[ms][ns] = __builtin_amdgcn_mfma_f32_32x32x16_bf16(
                        af[ms], bfr[ns], acc[ms][ns], 0, 0, 0);
        }
    }

    // ---- epilogue: block-local per-row max over all 256 codes ----
    float tmax[2] = {-1e30f, -1e30f};
#pragma unroll
    for (int ms = 0; ms < 4; ms++)
#pragma unroll
        for (int ns = 0; ns < 2; ns++)
#pragma unroll
            for (int r = 0; r < 16; r++)
                tmax[ns] = fmaxf(tmax[ns], acc[ms][ns][r]);
#pragma unroll
    for (int ns = 0; ns < 2; ns++)
        tmax[ns] = fmaxf(tmax[ns], __shfl_xor(tmax[ns], 32));

    __syncthreads();                 // GEMM LDS dead; reuse for rowmax + lcnt
    float* rmx  = (float*)smem;      // [2][256]: [wm][local row]
    int*   lcnt = (int*)(smem + 2048);   // [256] per-row slot counters
    if (lane < 32) {
        rmx[wm * 256 + wn * 64 + 0 * 32 + lane] = tmax[0];
        rmx[wm * 256 + wn * 64 + 1 * 32 + lane] = tmax[1];
    }
    if (tid < 256) lcnt[tid] = 0;
    __syncthreads();

    float thr[2];
#pragma unroll
    for (int ns = 0; ns < 2; ns++) {
        const int lr = wn * 64 + ns * 32 + m;
        thr[ns] = fmaxf(rmx[lr], rmx[256 + lr]) - MARGIN_T;
    }

    // ---- append keepers: LDS-atomic slot reservation + plain stores ----
#pragma unroll
    for (int ms = 0; ms < 4; ms++)
#pragma unroll
        for (int ns = 0; ns < 2; ns++)
#pragma unroll
            for (int r = 0; r < 16; r++) {
                float v = acc[ms][ns][r];
                if (v >= thr[ns]) {
                    const int lr = wn * 64 + ns * 32 + m;
                    int slot = atomicAdd(&lcnt[lr], 1);        // LDS atomic
                    if (slot < SLOTS) {
                        int code = codeBase + wm * 128 + ms * 32
                                 + ((r & 3) + 8 * (r >> 2) + 4 * half);
                        int b = __float_as_int(v);
                        unsigned key = (unsigned)b ^ ((unsigned)(b >> 31) | 0x80000000u);
                        unsigned entry = (key & 0xFFFFF000u) | (unsigned)code;
                        cand2[((size_t)(rowBase + lr) * 16 + cb) * SLOTS + slot] = entry;
                    }
                }
            }

    __syncthreads();
    if (tid < 256) {
        int cf = lcnt[tid];
        cnt8[(size_t)(rowBase + tid) * 16 + cb] =
            (cf > SLOTS) ? (unsigned char)255 : (unsigned char)cf;
        lmax[(size_t)(rowBase + tid) * 16 + cb] = fmaxf(rmx[tid], rmx[256 + tid]);
    }
}

// ---------------------------------------------------------------------------
// K_RESCORE v12: R9-proven argmin path (4 rows/block, wave per row, zero
// __syncthreads) + fused histogram. WRITES ONLY WS BUFFERS (idx_int,
// ccount) -- no d_out writes, because this kernel is the last reader of
// the d_out scratch (cand2/cnt8/lmax). R13's aliasing race is the reason.
// ---------------------------------------------------------------------------
__global__ __launch_bounds__(256) void k_rescore(
    const float* __restrict__ z, const float* __restrict__ w,
    const float* __restrict__ z2, const float* __restrict__ e2,
    const unsigned char* __restrict__ cnt8, const unsigned int* __restrict__ cand2,
    const float* __restrict__ lmax, int* __restrict__ idx_out,
    int* __restrict__ ccount)
{
#pragma clang fp contract(off)
    const int lane = threadIdx.x & 63;
    const int wv   = threadIdx.x >> 6;          // 0..3
    const int n    = blockIdx.x * 4 + wv;

    __shared__ float4 zst[4][64];               // 4 KB, wave-private slices
    __shared__ int    surv[4][CAP];             // 2 KB, wave-private slices

    zst[wv][lane] = ((const float4*)(z + (size_t)n * D_DIM))[lane];

    // ---- counts + exact global row max ----
    int   c  = 0;
    float lm = -1e30f;
    if (lane < 16) {
        c  = cnt8[(size_t)n * 16 + lane];
        lm = lmax[(size_t)n * 16 + lane];
    }
    float gm = lm;
#pragma unroll
    for (int off = 32; off > 0; off >>= 1)
        gm = fmaxf(gm, __shfl_xor(gm, off));    // wave-uniform exact max

    // mask of qualifying overflow blocks (bits 0..15); wave-uniform
    unsigned long long obal =
        __ballot((lane < 16) && (c == 255) && (lm >= gm - MARGIN_T));

    float bd = __builtin_inff(); int bk = K_CODES;
    const float z2v = z2[n];

    // ---- coalesced full-slice gather + filter (always) ----
    {
        const unsigned e0 = cand2[(size_t)n * 128 + lane];
        const unsigned e1 = cand2[(size_t)n * 128 + 64 + lane];
        const int craw0 = __shfl(c, lane >> 3);           // cb0 = lane>>3 (0..7)
        const int craw1 = __shfl(c, 8 + (lane >> 3));     // cb1 = 8+(lane>>3)
        const int cl0 = (craw0 == 255) ? SLOTS : craw0;
        const int cl1 = (craw1 == 255) ? SLOTS : craw1;
        const float thrF = gm - MARGIN_T - 1e-4f;         // key-truncation slack

        auto keyf = [](unsigned e) -> float {
            unsigned ky = e & 0xFFFFF000u;
            int b = (ky & 0x80000000u) ? (int)(ky ^ 0x80000000u) : (int)~ky;
            return __int_as_float(b);
        };
        const bool keep0 = ((lane & 7) < cl0) && (keyf(e0) >= thrF);
        const bool keep1 = ((lane & 7) < cl1) && (keyf(e1) >= thrF);

        unsigned long long bal0 = __ballot(keep0);
        unsigned long long bal1 = __ballot(keep1);
        const unsigned long long below = (1ull << lane) - 1ull;
        const int n0 = (int)__popcll(bal0);
        if (keep0) surv[wv][(int)__popcll(bal0 & below)] = (int)(e0 & 0xFFFu);
        if (keep1) surv[wv][n0 + (int)__popcll(bal1 & below)] = (int)(e1 & 0xFFFu);
        const int nt = n0 + (int)__popcll(bal1);

        // ---- per-lane exact survivor chains (nt typically 1-3) ----
        for (int s = lane; s < nt; s += 64) {
            int k = surv[wv][s];
            if ((unsigned)k >= (unsigned)K_CODES) k = 0;  // defensive
            const float4* wp = (const float4*)(w + (size_t)k * D_DIM);
            float tacc = 0.0f;
#pragma unroll 8
            for (int d4 = 0; d4 < 64; d4++) {
                float4 wvv = wp[d4];
                float4 zv  = zst[wv][d4];
                tacc = __builtin_fmaf(zv.x, wvv.x, tacc);
                tacc = __builtin_fmaf(zv.y, wvv.y, tacc);
                tacc = __builtin_fmaf(zv.z, wvv.z, tacc);
                tacc = __builtin_fmaf(zv.w, wvv.w, tacc);
            }
            float u  = z2v - 2.0f * tacc;   // 2*tacc exact -> single rounding
            float dv = u + e2[k];
            if (dv < bd || (dv == bd && k < bk)) { bd = dv; bk = k; }
        }
    }

    // ---- per-block exact recovery of qualifying overflow blocks (rare) ----
    while (obal) {
        const int cbq = (int)(__ffsll((long long)obal) - 1);
        obal &= obal - 1ull;
        const int k0 = cbq * 256 + lane;      // lane's 4 codes: +0,+64,+128,+192
        const float4* w0 = (const float4*)(w + (size_t)(k0      ) * D_DIM);
        const float4* w1 = (const float4*)(w + (size_t)(k0 +  64) * D_DIM);
        const float4* w2 = (const float4*)(w + (size_t)(k0 + 128) * D_DIM);
        const float4* w3 = (const float4*)(w + (size_t)(k0 + 192) * D_DIM);
        float t0 = 0.0f, t1 = 0.0f, t2 = 0.0f, t3 = 0.0f;
#pragma unroll 8
        for (int d4 = 0; d4 < 64; d4++) {
            float4 zv = zst[wv][d4];          // LDS broadcast
            float4 a0 = w0[d4];
            float4 a1 = w1[d4];
            float4 a2 = w2[d4];
            float4 a3 = w3[d4];
            t0 = __builtin_fmaf(zv.x, a0.x, t0);
            t1 = __builtin_fmaf(zv.x, a1.x, t1);
            t2 = __builtin_fmaf(zv.x, a2.x, t2);
            t3 = __builtin_fmaf(zv.x, a3.x, t3);
            t0 = __builtin_fmaf(zv.y, a0.y, t0);
            t1 = __builtin_fmaf(zv.y, a1.y, t1);
            t2 = __builtin_fmaf(zv.y, a2.y, t2);
            t3 = __builtin_fmaf(zv.y, a3.y, t3);
            t0 = __builtin_fmaf(zv.z, a0.z, t0);
            t1 = __builtin_fmaf(zv.z, a1.z, t1);
            t2 = __builtin_fmaf(zv.z, a2.z, t2);
            t3 = __builtin_fmaf(zv.z, a3.z, t3);
            t0 = __builtin_fmaf(zv.w, a0.w, t0);
            t1 = __builtin_fmaf(zv.w, a1.w, t1);
            t2 = __builtin_fmaf(zv.w, a2.w, t2);
            t3 = __builtin_fmaf(zv.w, a3.w, t3);
        }
        float d0 = (z2v - 2.0f * t0) + e2[k0];
        float d1 = (z2v - 2.0f * t1) + e2[k0 + 64];
        float d2 = (z2v - 2.0f * t2) + e2[k0 + 128];
        float d3 = (z2v - 2.0f * t3) + e2[k0 + 192];
        if (d0 < bd || (d0 == bd && k0       < bk)) { bd = d0; bk = k0; }
        if (d1 < bd || (d1 == bd && k0 +  64 < bk)) { bd = d1; bk = k0 + 64; }
        if (d2 < bd || (d2 == bd && k0 + 128 < bk)) { bd = d2; bk = k0 + 128; }
        if (d3 < bd || (d3 == bd && k0 + 192 < bk)) { bd = d3; bk = k0 + 192; }
    }

#pragma unroll
    for (int off = 1; off < 64; off <<= 1) {
        float od = __shfl_xor(bd, off);
        int   ok = __shfl_xor(bk, off);
        if (od < bd || (od == bd && ok < bk)) { bd = od; bk = ok; }
    }
    if (lane == 0) {
        const int fk = (bk < K_CODES && bk >= 0) ? bk : 0;
        idx_out[n] = fk;
        atomicAdd(&ccount[fk], 1);          // fused histogram (ws only)
    }
}

// ---------------------------------------------------------------------------
// K3 v4: wave-per-row (4 rows/block), ZERO atomics, zero __syncthreads.
// Runs AFTER rescore so d_out writes are safe. zq = zv+(wq-zv) identical
// rounding; loss via __shfl_xor wave sum (the exact order that passed R11).
// ---------------------------------------------------------------------------
__global__ __launch_bounds__(256) void k3_scatter(
    const float* __restrict__ z, const float* __restrict__ w,
    const int* __restrict__ idx_in,
    float* __restrict__ lossp, float* __restrict__ out_zq,
    float* __restrict__ out_idx)
{
#pragma clang fp contract(off)
    const int lane = threadIdx.x & 63;
    const int wv   = threadIdx.x >> 6;          // 0..3
    const int n    = blockIdx.x * 4 + wv;

    int idx = idx_in[n];                        // wave-uniform
    if (idx < 0) idx = 0;
    if (idx >= K_CODES) idx = K_CODES - 1;      // defensive clamp

    float4 zv = ((const float4*)(z + (size_t)n   * D_DIM))[lane];
    float4 wq = ((const float4*)(w + (size_t)idx * D_DIM))[lane];

    float4 q;
    q.x = zv.x + (wq.x - zv.x);
    q.y = zv.y + (wq.y - zv.y);
    q.z = zv.z + (wq.z - zv.z);
    q.w = zv.w + (wq.w - zv.w);
    ((float4*)(out_zq + (size_t)n * D_DIM))[lane] = q;

    float dx = zv.x - wq.x, dy = zv.y - wq.y, dz = zv.z - wq.z, dwc = zv.w - wq.w;
    float sq = ((dx * dx + dy * dy) + (dz * dz + dwc * dwc));
#pragma unroll
    for (int off = 1; off < 64; off <<= 1)
        sq += __shfl_xor(sq, off);

    if (lane == 0) {
        out_idx[n] = (float)idx;
        lossp[n]   = sq;
    }
}

// ---------------------------------------------------------------------------
// K_PREFIX_CS: single block 1024 thr. Fuses int prefix scan (-> starts,
// cursor) and k4 (loss finalize + Laplace-smoothed new_cs) with identical
// reduction/scan orders; counts from the exact int histogram.
// ---------------------------------------------------------------------------
__global__ void k_prefix_cs(const float* __restrict__ lossp,
                            const int* __restrict__ ccount,
                            const float* __restrict__ cs_in,
                            int* __restrict__ starts, int* __restrict__ cursor,
                            float* __restrict__ out_loss, float* __restrict__ out_cs)
{
#pragma clang fp contract(off)
    const int t = threadIdx.x;
    __shared__ float red[1024];
    __shared__ float pre[K_CODES];
    __shared__ int   s[1024];

    // ---- loss finalize (identical to k4 phase 1) ----
    float sacc = 0.0f;
    for (int i = t; i < N_ROWS; i += 1024) sacc += lossp[i];
    red[t] = sacc; __syncthreads();
    for (int st = 512; st > 0; st >>= 1) {
        if (t < st) red[t] += red[t + st];
        __syncthreads();
    }
    if (t == 0) out_loss[0] = 0.25f * (red[0] / 8388608.0f);
    __syncthreads();

    // ---- int prefix scan (identical to old k_prefix) ----
    int c0 = ccount[t * 4 + 0];
    int c1 = ccount[t * 4 + 1];
    int c2 = ccount[t * 4 + 2];
    int c3 = ccount[t * 4 + 3];
    int tsum = ((c0 + c1) + (c2 + c3));
    s[t] = tsum;
    __syncthreads();
    for (int off = 1; off < 1024; off <<= 1) {
        int v = (t >= off) ? s[t - off] : 0;
        __syncthreads();
        s[t] += v;
        __syncthreads();
    }
    int base = s[t] - tsum;          // exclusive
    starts[t * 4 + 0] = base;
    starts[t * 4 + 1] = base + c0;
    starts[t * 4 + 2] = base + c0 + c1;
    starts[t * 4 + 3] = base + c0 + c1 + c2;
    cursor[t * 4 + 0] = base;
    cursor[t * 4 + 1] = base + c0;
    cursor[t * 4 + 2] = base + c0 + c1;
    cursor[t * 4 + 3] = base + c0 + c1 + c2;

    // ---- new_cs (identical to k4 phase 2) ----
    const float DEC = 0.99f;
    const float OMD = (float)(1.0 - 0.99);
    float mine[4];
#pragma unroll
    for (int q = 0; q < 4; q++) {
        int k = t + q * 1024;
        float t1 = DEC * cs_in[k];
        float t2 = OMD * (float)ccount[k];
        float p = t1 + t2;
        pre[k] = p; mine[q] = p;
    }
    float psum = (mine[0] + mine[1]) + (mine[2] + mine[3]);
    red[t] = psum; __syncthreads();
    for (int st = 512; st > 0; st >>= 1) {
        if (t < st) red[t] += red[t + st];
        __syncthreads();
    }
    float nsum = red[0];
    const float KEPS = (float)(4096.0 * 1e-5);
    float denom = nsum + KEPS;
#pragma unroll
    for (int q = 0; q < 4; q++) {
        int k = t + q * 1024;
        float v = ((pre[k] + 1e-5f) / denom) * nsum;
        out_cs[k] = v;
    }
}

// ---------------------------------------------------------------------------
// K_FILL: bucket row ids (32768 atomics on cursor).
// ---------------------------------------------------------------------------
__global__ void k_fill(const int* __restrict__ idx_in, int* __restrict__ cursor,
                       int* __restrict__ rows)
{
    int n = blockIdx.x * 256 + threadIdx.x;
    int idx = idx_in[n];
    if (idx < 0) idx = 0;
    if (idx >= K_CODES) idx = K_CODES - 1;
    int pos = atomicAdd(&cursor[idx], 1);
    rows[pos] = n;
}

// ---------------------------------------------------------------------------
// K5 v2: block-per-code gather-sum dw (proven R12). Thread t owns dim t;
// iterates the code's bucket rows with coalesced 1KB z-row reads, register
// accumulate, then the identical EMA/divide.
// ---------------------------------------------------------------------------
__global__ void k5_emaw(const float* __restrict__ z, const float* __restrict__ ema_w,
                        const int* __restrict__ starts, const int* __restrict__ ccount,
                        const int* __restrict__ rows, const float* __restrict__ newcs,
                        float* __restrict__ out_w, float* __restrict__ out_emaw)
{
#pragma clang fp contract(off)
    const int k = blockIdx.x;
    const int t = threadIdx.x;
    const int s = starts[k];
    const int e = s + ccount[k];

    float acc = 0.0f;
    for (int r = s; r < e; r++) {
        int row = rows[r];
        acc += z[(size_t)row * D_DIM + t];
    }

    const float OMD = (float)(1.0 - 0.99);
    float t1 = 0.99f * ema_w[(size_t)k * D_DIM + t];
    float t2 = OMD * acc;
    float ne = t1 + t2;
    out_emaw[(size_t)k * D_DIM + t] = ne;
    out_w[(size_t)k * D_DIM + t] = ne / newcs[k];
}

extern "C" void kernel_launch(void* const* d_in, const int* in_sizes, int n_in,
                              void* d_out, int out_size, void* d_ws, size_t ws_size,
                              hipStream_t stream)
{
    const float* z    = (const float*)d_in[0];
    const float* w    = (const float*)d_in[1];
    const float* cs   = (const float*)d_in[2];
    const float* emaw = (const float*)d_in[3];

    float* out      = (float*)d_out;
    float* out_zq   = out;                    // 8388608
    float* out_idx  = out + 8388608;          // 32768
    float* out_loss = out + 8421376;          // 1
    float* out_w    = out + 8421377;          // 1048576
    float* out_cs   = out + 9469953;          // 4096
    float* out_emaw = out + 9474049;          // 1048576

    char* ws = (char*)d_ws;
    float*          lossp   = (float*)(ws + WS_LOSSP);
    int*            idx_int = (int*)  (ws + WS_IDX);
    float*          z2      = (float*)(ws + WS_Z2);
    float*          e2      = (float*)(ws + WS_E2);
    int*            ccount  = (int*)  (ws + WS_CCOUNT);
    int*            starts  = (int*)  (ws + WS_STARTS);
    int*            cursor  = (int*)  (ws + WS_CURSOR);
    int*            rowsb   = (int*)  (ws + WS_ROWS);

    // big scratch in d_out: consumed entirely by k_rescore; NO kernel before
    // or during rescore may write d_out (R13 aliasing-race lesson).
    char* ob = (char*)d_out;
    unsigned short* zb    = (unsigned short*)(ob + DO_ZB);
    unsigned short* wb    = (unsigned short*)(ob + DO_WB);
    unsigned int*   cand2 = (unsigned int*)  (ob + DO_CAND);
    unsigned char*  cnt8  = (unsigned char*) (ob + DO_CNT8);
    float*          lmx   = (float*)         (ob + DO_LMAX);

    hipMemsetAsync(ccount, 0, K_CODES * sizeof(int), stream);

    // fused k1 + kconv: blocks [0,145) = norms, [145,1297) = bf16 panels
    k1_kconv<<<1297, 256, 0, stream>>>(z, w, z2, e2, zb, wb);

    dim3 g2(16, 128);   // x = code-block, y = row-block (swizzled in-kernel)
    k2_scan<<<g2, 512, 0, stream>>>(zb, wb, cnt8, cand2, lmx);

    // fused rescore + histogram: ws writes only (last reader of d_out scratch)
    k_rescore<<<N_ROWS / 4, 256, 0, stream>>>(z, w, z2, e2, cnt8, cand2, lmx,
                                              idx_int, ccount);

    // d_out writes begin here (scratch is dead)
    k3_scatter<<<N_ROWS / 4, 256, 0, stream>>>(z, w, idx_int, lossp,
                                               out_zq, out_idx);

    // fused prefix + k4
    k_prefix_cs<<<1, 1024, 0, stream>>>(lossp, ccount, cs, starts, cursor,
                                        out_loss, out_cs);

    k_fill<<<N_ROWS / 256, 256, 0, stream>>>(idx_int, cursor, rowsb);

    k5_emaw<<<K_CODES, 256, 0, stream>>>(z, emaw, starts, ccount, rowsb,
                                         out_cs, out_w, out_emaw);
}